// Round 10
// baseline (465.509 us; speedup 1.0000x reference)
//
#include <hip/hip_runtime.h>
#include <hip/hip_cooperative_groups.h>
#include <cfloat>

namespace cg = cooperative_groups;

// EmbeddingBag(mean) ++ EmbeddingBag(max) -> Linear(no bias)
// feat[T] i32, offs[B] i32 (sorted, offs[0]=0), W[100000][128] f32,
// L[128][256] f32 ; out: [B][128] f32
// Bag b = tokens [offs[b], offs[b+1]) (offs[B]=T); empty bag -> mean=max=0.
//
// Single cooperative kernel (one dispatch):
//  phase0: zero ws accumulators            -> grid.sync()
//  phase1: token-uniform gather (R tokens/wave, perfectly balanced),
//          per-segment partials flushed via atomicAdd / atomicMax(key)
//  phase2: grid.sync() -> finalize mean/max, dense [4x256]x[256x128]/block

constexpr int D     = 128;
constexpr int TYPES = 128;
constexpr int K2BPB = 4;     // bags per block in linear phase
constexpr int GRID  = 2048;  // co-resident: 8 blocks/CU x 256 CU
constexpr int BLOCK = 256;

// order-preserving float->uint key (monotone): uint-compare == float-compare
__device__ __forceinline__ unsigned fkey(float f) {
    unsigned b = __float_as_uint(f);
    return (b & 0x80000000u) ? ~b : (b | 0x80000000u);
}
__device__ __forceinline__ float funkey(unsigned k) {
    return __uint_as_float((k & 0x80000000u) ? (k & 0x7FFFFFFFu) : ~k);
}

__global__ __launch_bounds__(BLOCK, 8)
void fused_embbag(const int* __restrict__ feat, const int* __restrict__ offs,
                  const float* __restrict__ W, const float* __restrict__ L,
                  float* __restrict__ out,
                  float* __restrict__ wsum, unsigned* __restrict__ wkey,
                  int T, int B)
{
    __shared__ float men[K2BPB][2 * D];       // 4 KB
    __shared__ float partial[K2BPB][TYPES];   // 2 KB

    cg::grid_group grid = cg::this_grid();
    const int tid = threadIdx.x;

    // ---------------- phase 0: zero accumulators ---------------------------
    {
        float4* acc4 = reinterpret_cast<float4*>(wsum);   // wsum||wkey contiguous
        const int nacc4 = (B * D * 2) / 4;
        for (int z = blockIdx.x * BLOCK + tid; z < nacc4; z += GRID * BLOCK)
            acc4[z] = make_float4(0.f, 0.f, 0.f, 0.f);
    }
    grid.sync();

    // ---------------- phase 1: token-uniform gather ------------------------
    {
        const int wave = blockIdx.x * (BLOCK / 64) + (tid >> 6);
        const int nw   = GRID * (BLOCK / 64);
        const int lane = tid & 63;
        const int slot = lane >> 5;   // 0/1: alternating tokens
        const int g    = lane & 31;   // dims 4g..4g+3
        const int R    = (T + nw - 1) / nw;
        const long long i0w = (long long)wave * R;

        if (i0w < T) {
            const int iw = (int)min((long long)T, i0w + R);

            // segment of first token (uniform across lanes, ~13 iters)
            int lo = 0, hi = B;
            while (lo < hi) {
                const int mid = (lo + hi) >> 1;
                if (offs[mid] <= (int)i0w) lo = mid + 1; else hi = mid;
            }
            int seg    = lo - 1;
            int segEnd = (seg + 1 < B) ? offs[seg + 1] : T;

            const float* __restrict__ Wg = W + 4 * g;

            for (int c0 = (int)i0w; c0 < iw; c0 += 64) {
                const int nvalid = min(64, iw - c0);
                const int iend   = c0 + nvalid;
                // subchunk token ids: one coalesced load, lane j = token c0+j
                const int idxreg = feat[min(c0 + lane, T - 1)];

                float4 s4 = make_float4(0.f, 0.f, 0.f, 0.f);
                float4 m4 = make_float4(-FLT_MAX, -FLT_MAX, -FLT_MAX, -FLT_MAX);
                bool dirty = false;
                int i = c0;

                while (true) {
                    const int stop = min(iend, segEnd);
                    int len = stop - i;
                    if (len > 0) {
                        dirty = true;
                        // full 16-token batches: 8 gathers in flight per lane
                        for (; len >= 16; len -= 16, i += 16) {
                            int idx[8];
                            #pragma unroll
                            for (int u = 0; u < 8; ++u)
                                idx[u] = __shfl(idxreg, (i - c0) + 2 * u + slot);
                            float4 v[8];
                            #pragma unroll
                            for (int u = 0; u < 8; ++u)
                                v[u] = *reinterpret_cast<const float4*>(
                                           Wg + (size_t)idx[u] * D);
                            #pragma unroll
                            for (int u = 0; u < 8; ++u) {
                                s4.x += v[u].x; s4.y += v[u].y;
                                s4.z += v[u].z; s4.w += v[u].w;
                                m4.x = fmaxf(m4.x, v[u].x);
                                m4.y = fmaxf(m4.y, v[u].y);
                                m4.z = fmaxf(m4.z, v[u].z);
                                m4.w = fmaxf(m4.w, v[u].w);
                            }
                        }
                        if (len > 0) {   // predicated tail, 1..15 tokens
                            int idx[8]; bool val[8];
                            #pragma unroll
                            for (int u = 0; u < 8; ++u) {
                                const int t = i + 2 * u + slot;
                                val[u] = (t < stop);
                                idx[u] = __shfl(idxreg,
                                                (val[u] ? t : stop - 1) - c0);
                            }
                            float4 v[8];
                            #pragma unroll
                            for (int u = 0; u < 8; ++u)
                                v[u] = *reinterpret_cast<const float4*>(
                                           Wg + (size_t)idx[u] * D);
                            #pragma unroll
                            for (int u = 0; u < 8; ++u) {
                                s4.x += val[u] ? v[u].x : 0.f;
                                s4.y += val[u] ? v[u].y : 0.f;
                                s4.z += val[u] ? v[u].z : 0.f;
                                s4.w += val[u] ? v[u].w : 0.f;
                                m4.x = fmaxf(m4.x, val[u] ? v[u].x : -FLT_MAX);
                                m4.y = fmaxf(m4.y, val[u] ? v[u].y : -FLT_MAX);
                                m4.z = fmaxf(m4.z, val[u] ? v[u].z : -FLT_MAX);
                                m4.w = fmaxf(m4.w, val[u] ? v[u].w : -FLT_MAX);
                            }
                            i = stop;
                        }
                    }

                    const bool done = (i >= iend);
                    if (dirty && (done || i >= segEnd)) {
                        // merge slot halves (lane ^ 32); 64-lane atomic flush
                        s4.x += __shfl_xor(s4.x, 32); s4.y += __shfl_xor(s4.y, 32);
                        s4.z += __shfl_xor(s4.z, 32); s4.w += __shfl_xor(s4.w, 32);
                        m4.x = fmaxf(m4.x, __shfl_xor(m4.x, 32));
                        m4.y = fmaxf(m4.y, __shfl_xor(m4.y, 32));
                        m4.z = fmaxf(m4.z, __shfl_xor(m4.z, 32));
                        m4.w = fmaxf(m4.w, __shfl_xor(m4.w, 32));
                        const float a0 = slot ? s4.z : s4.x;
                        const float a1 = slot ? s4.w : s4.y;
                        const float b0 = slot ? m4.z : m4.x;
                        const float b1 = slot ? m4.w : m4.y;
                        float*    ps = wsum + (size_t)seg * D + 4 * g + 2 * slot;
                        unsigned* pk = wkey + (size_t)seg * D + 4 * g + 2 * slot;
                        atomicAdd(ps + 0, a0); atomicAdd(ps + 1, a1);
                        atomicMax(pk + 0, fkey(b0)); atomicMax(pk + 1, fkey(b1));
                        s4 = make_float4(0.f, 0.f, 0.f, 0.f);
                        m4 = make_float4(-FLT_MAX, -FLT_MAX, -FLT_MAX, -FLT_MAX);
                        dirty = false;
                    }
                    if (done) break;
                    ++seg;
                    segEnd = (seg + 1 < B) ? offs[seg + 1] : T;
                }
            }
        }
    }
    grid.sync();

    // ---------------- phase 2: finalize + linear ---------------------------
    for (int bag0 = blockIdx.x * K2BPB; bag0 < B; bag0 += GRID * K2BPB) {
        // finalize mean / max into LDS (float4-vectorized)
        for (int e = tid; e < K2BPB * 2 * D / 4; e += BLOCK) {
            const int r   = e >> 6;          // bag slot (64 float4 per row)
            const int c   = e & 63;
            const int bag = bag0 + r;
            float4 v = make_float4(0.f, 0.f, 0.f, 0.f);
            if (bag < B) {
                const int st  = offs[bag];
                const int en  = (bag + 1 < B) ? offs[bag + 1] : T;
                const int cnt = en - st;
                if (cnt > 0) {
                    if (c < 32) {
                        const float4 s = *reinterpret_cast<const float4*>(
                            wsum + (size_t)bag * D + 4 * c);
                        const float inv = 1.0f / (float)cnt;
                        v = make_float4(s.x * inv, s.y * inv, s.z * inv, s.w * inv);
                    } else {
                        const uint4 k = *reinterpret_cast<const uint4*>(
                            wkey + (size_t)bag * D + 4 * (c - 32));
                        v = make_float4(funkey(k.x), funkey(k.y),
                                        funkey(k.z), funkey(k.w));
                    }
                }
            }
            *reinterpret_cast<float4*>(&men[r][4 * c]) = v;
        }
        __syncthreads();

        const int o = tid & (TYPES - 1);
        const int h = tid >> 7;          // K-half: 0 or 1
        float acc[K2BPB];
        #pragma unroll
        for (int b = 0; b < K2BPB; ++b) acc[b] = 0.f;

        const float* Lrow = L + (size_t)o * (2 * D) + h * D;
        #pragma unroll 4
        for (int k4 = 0; k4 < D / 4; ++k4) {
            const float4 lv = *reinterpret_cast<const float4*>(Lrow + 4 * k4);
            #pragma unroll
            for (int b = 0; b < K2BPB; ++b) {
                const float4 mv =
                    *reinterpret_cast<const float4*>(&men[b][h * D + 4 * k4]);
                acc[b] = fmaf(lv.x, mv.x, acc[b]);
                acc[b] = fmaf(lv.y, mv.y, acc[b]);
                acc[b] = fmaf(lv.z, mv.z, acc[b]);
                acc[b] = fmaf(lv.w, mv.w, acc[b]);
            }
        }
        if (h == 1) {
            #pragma unroll
            for (int b = 0; b < K2BPB; ++b) partial[b][o] = acc[b];
        }
        __syncthreads();
        if (h == 0) {
            #pragma unroll
            for (int b = 0; b < K2BPB; ++b) {
                const int bag = bag0 + b;
                if (bag < B)
                    out[(size_t)bag * TYPES + o] = acc[b] + partial[b][o];
            }
        }
        __syncthreads();
    }
}

// ================= fallback A: 3-kernel pipeline (round-7) ==================
constexpr int TPW   = 64;
constexpr int FK2B  = 8;

__global__ __launch_bounds__(256)
void k0_init(const int* __restrict__ offs, int* __restrict__ waveseg,
             float4* __restrict__ acc4, int nacc4, int T, int B, int nwave)
{
    const int tid = blockIdx.x * 256 + threadIdx.x;
    for (int z = tid; z < nacc4; z += gridDim.x * 256)
        acc4[z] = make_float4(0.f, 0.f, 0.f, 0.f);
    if (tid < nwave) {
        const int i0 = tid * TPW;
        int lo = 0, hi = B;
        while (lo < hi) {
            const int mid = (lo + hi) >> 1;
            if (offs[mid] <= i0) lo = mid + 1; else hi = mid;
        }
        waveseg[tid] = lo - 1;
    }
}

__global__ __launch_bounds__(256, 4)
void k1_gather(const int* __restrict__ feat, const int* __restrict__ offs,
               const int* __restrict__ waveseg, const float* __restrict__ W,
               float* __restrict__ wsum, unsigned* __restrict__ wkey,
               int T, int B)
{
    const int wave = blockIdx.x * 4 + (threadIdx.x >> 6);
    const int lane = threadIdx.x & 63;
    const int slot = lane >> 5;
    const int g    = lane & 31;
    const int i0   = wave * TPW;
    if (i0 >= T) return;
    const int iend = min(i0 + TPW, T);
    const int idxreg = feat[min(i0 + lane, T - 1)];

    int seg    = waveseg[wave];
    int segEnd = (seg + 1 < B) ? offs[seg + 1] : T;

    const float* __restrict__ Wg = W + 4 * g;
    float4 s4 = make_float4(0.f, 0.f, 0.f, 0.f);
    float4 m4 = make_float4(-FLT_MAX, -FLT_MAX, -FLT_MAX, -FLT_MAX);
    bool dirty = false;
    int i = i0;

    while (true) {
        const int stop = min(iend, segEnd);
        int len = stop - i;
        if (len > 0) {
            dirty = true;
            for (; len >= 16; len -= 16, i += 16) {
                int idx[8];
                #pragma unroll
                for (int u = 0; u < 8; ++u)
                    idx[u] = __shfl(idxreg, (i - i0) + 2 * u + slot);
                float4 v[8];
                #pragma unroll
                for (int u = 0; u < 8; ++u)
                    v[u] = *reinterpret_cast<const float4*>(Wg + (size_t)idx[u] * D);
                #pragma unroll
                for (int u = 0; u < 8; ++u) {
                    s4.x += v[u].x; s4.y += v[u].y;
                    s4.z += v[u].z; s4.w += v[u].w;
                    m4.x = fmaxf(m4.x, v[u].x); m4.y = fmaxf(m4.y, v[u].y);
                    m4.z = fmaxf(m4.z, v[u].z); m4.w = fmaxf(m4.w, v[u].w);
                }
            }
            if (len > 0) {
                int idx[8]; bool val[8];
                #pragma unroll
                for (int u = 0; u < 8; ++u) {
                    const int t = i + 2 * u + slot;
                    val[u] = (t < stop);
                    idx[u] = __shfl(idxreg, (val[u] ? t : stop - 1) - i0);
                }
                float4 v[8];
                #pragma unroll
                for (int u = 0; u < 8; ++u)
                    v[u] = *reinterpret_cast<const float4*>(Wg + (size_t)idx[u] * D);
                #pragma unroll
                for (int u = 0; u < 8; ++u) {
                    s4.x += val[u] ? v[u].x : 0.f;
                    s4.y += val[u] ? v[u].y : 0.f;
                    s4.z += val[u] ? v[u].z : 0.f;
                    s4.w += val[u] ? v[u].w : 0.f;
                    m4.x = fmaxf(m4.x, val[u] ? v[u].x : -FLT_MAX);
                    m4.y = fmaxf(m4.y, val[u] ? v[u].y : -FLT_MAX);
                    m4.z = fmaxf(m4.z, val[u] ? v[u].z : -FLT_MAX);
                    m4.w = fmaxf(m4.w, val[u] ? v[u].w : -FLT_MAX);
                }
                i = stop;
            }
        }
        const bool done = (i >= iend);
        if (dirty && (done || i >= segEnd)) {
            s4.x += __shfl_xor(s4.x, 32); s4.y += __shfl_xor(s4.y, 32);
            s4.z += __shfl_xor(s4.z, 32); s4.w += __shfl_xor(s4.w, 32);
            m4.x = fmaxf(m4.x, __shfl_xor(m4.x, 32));
            m4.y = fmaxf(m4.y, __shfl_xor(m4.y, 32));
            m4.z = fmaxf(m4.z, __shfl_xor(m4.z, 32));
            m4.w = fmaxf(m4.w, __shfl_xor(m4.w, 32));
            const float a0 = slot ? s4.z : s4.x;
            const float a1 = slot ? s4.w : s4.y;
            const float b0 = slot ? m4.z : m4.x;
            const float b1 = slot ? m4.w : m4.y;
            float*    ps = wsum + (size_t)seg * D + 4 * g + 2 * slot;
            unsigned* pk = wkey + (size_t)seg * D + 4 * g + 2 * slot;
            atomicAdd(ps + 0, a0); atomicAdd(ps + 1, a1);
            atomicMax(pk + 0, fkey(b0)); atomicMax(pk + 1, fkey(b1));
            s4 = make_float4(0.f, 0.f, 0.f, 0.f);
            m4 = make_float4(-FLT_MAX, -FLT_MAX, -FLT_MAX, -FLT_MAX);
            dirty = false;
        }
        if (done) break;
        ++seg;
        segEnd = (seg + 1 < B) ? offs[seg + 1] : T;
    }
}

__global__ __launch_bounds__(256, 8)
void k2_linear(const int* __restrict__ offs,
               const float* __restrict__ wsum, const unsigned* __restrict__ wkey,
               const float* __restrict__ L, float* __restrict__ out,
               int T, int B)
{
    __shared__ float men[FK2B][2 * D];
    __shared__ float partial[FK2B][TYPES];
    const int tid  = threadIdx.x;
    const int bag0 = blockIdx.x * FK2B;

    for (int e = tid; e < FK2B * 2 * D / 4; e += 256) {
        const int r   = e >> 6;
        const int c   = e & 63;
        const int bag = bag0 + r;
        float4 v = make_float4(0.f, 0.f, 0.f, 0.f);
        if (bag < B) {
            const int st  = offs[bag];
            const int en  = (bag + 1 < B) ? offs[bag + 1] : T;
            const int cnt = en - st;
            if (cnt > 0) {
                if (c < 32) {
                    const float4 s = *reinterpret_cast<const float4*>(
                        wsum + (size_t)bag * D + 4 * c);
                    const float inv = 1.0f / (float)cnt;
                    v = make_float4(s.x * inv, s.y * inv, s.z * inv, s.w * inv);
                } else {
                    const uint4 k = *reinterpret_cast<const uint4*>(
                        wkey + (size_t)bag * D + 4 * (c - 32));
                    v = make_float4(funkey(k.x), funkey(k.y),
                                    funkey(k.z), funkey(k.w));
                }
            }
        }
        *reinterpret_cast<float4*>(&men[r][4 * c]) = v;
    }
    __syncthreads();

    const int o = tid & (TYPES - 1);
    const int h = tid >> 7;
    float acc[FK2B];
    #pragma unroll
    for (int b = 0; b < FK2B; ++b) acc[b] = 0.f;

    const float* Lrow = L + (size_t)o * (2 * D) + h * D;
    #pragma unroll 4
    for (int k4 = 0; k4 < D / 4; ++k4) {
        const float4 lv = *reinterpret_cast<const float4*>(Lrow + 4 * k4);
        #pragma unroll
        for (int b = 0; b < FK2B; ++b) {
            const float4 mv = *reinterpret_cast<const float4*>(&men[b][h * D + 4 * k4]);
            acc[b] = fmaf(lv.x, mv.x, acc[b]);
            acc[b] = fmaf(lv.y, mv.y, acc[b]);
            acc[b] = fmaf(lv.z, mv.z, acc[b]);
            acc[b] = fmaf(lv.w, mv.w, acc[b]);
        }
    }
    if (h == 1) {
        #pragma unroll
        for (int b = 0; b < FK2B; ++b) partial[b][o] = acc[b];
    }
    __syncthreads();
    if (h == 0) {
        #pragma unroll
        for (int b = 0; b < FK2B; ++b) {
            const int bag = bag0 + b;
            if (bag < B)
                out[(size_t)bag * TYPES + o] = acc[b] + partial[b][o];
        }
    }
}

// ============ fallback B: fused bag-parallel (round-4), no ws ===============
constexpr int FBPB = 4;
__global__ __launch_bounds__(512, 8)
void embbag_fallback(const int* __restrict__ feat, const int* __restrict__ offs,
                     const float* __restrict__ W, const float* __restrict__ L,
                     float* __restrict__ out, int T, int B)
{
    __shared__ float4 men[FBPB][64];
    __shared__ float4 redS[FBPB][2][32];
    __shared__ float4 redM[FBPB][2][32];
    __shared__ float  partial[3][FBPB][TYPES];
    const int tid = threadIdx.x, wv = tid >> 6, lane = tid & 63;
    const int bi = wv >> 1, wh = wv & 1, slot = lane >> 5, g = lane & 31;
    const int bag0 = blockIdx.x * FBPB, bag = bag0 + bi;
    int start = 0, end = 0;
    if (bag < B) { start = offs[bag]; end = (bag + 1 < B) ? offs[bag + 1] : T; }
    const int n = end - start, q = wh * 2 + slot;
    const int qa = start + (n * q) / 4, qb = start + (n * (q + 1)) / 4;
    float4 s4 = make_float4(0.f, 0.f, 0.f, 0.f);
    float4 m4 = make_float4(-FLT_MAX, -FLT_MAX, -FLT_MAX, -FLT_MAX);
    const float* Wg = W + 4 * g;
    int i = qa;
    for (; i + 8 <= qb; i += 8) {
        int idx[8];
        #pragma unroll
        for (int j = 0; j < 8; ++j) idx[j] = feat[i + j];
        #pragma unroll
        for (int j = 0; j < 8; ++j) {
            const float4 v = *reinterpret_cast<const float4*>(Wg + (size_t)idx[j] * D);
            s4.x += v.x; s4.y += v.y; s4.z += v.z; s4.w += v.w;
            m4.x = fmaxf(m4.x, v.x); m4.y = fmaxf(m4.y, v.y);
            m4.z = fmaxf(m4.z, v.z); m4.w = fmaxf(m4.w, v.w);
        }
    }
    for (; i < qb; ++i) {
        const int idx = feat[i];
        const float4 v = *reinterpret_cast<const float4*>(Wg + (size_t)idx * D);
        s4.x += v.x; s4.y += v.y; s4.z += v.z; s4.w += v.w;
        m4.x = fmaxf(m4.x, v.x); m4.y = fmaxf(m4.y, v.y);
        m4.z = fmaxf(m4.z, v.z); m4.w = fmaxf(m4.w, v.w);
    }
    s4.x += __shfl_xor(s4.x, 32); s4.y += __shfl_xor(s4.y, 32);
    s4.z += __shfl_xor(s4.z, 32); s4.w += __shfl_xor(s4.w, 32);
    m4.x = fmaxf(m4.x, __shfl_xor(m4.x, 32));
    m4.y = fmaxf(m4.y, __shfl_xor(m4.y, 32));
    m4.z = fmaxf(m4.z, __shfl_xor(m4.z, 32));
    m4.w = fmaxf(m4.w, __shfl_xor(m4.w, 32));
    if (lane < 32) { redS[bi][wh][g] = s4; redM[bi][wh][g] = m4; }
    __syncthreads();
    if (wh == 0 && lane < 32) {
        const float4 a0 = redS[bi][0][g], a1 = redS[bi][1][g];
        const float4 b0 = redM[bi][0][g], b1 = redM[bi][1][g];
        const bool empty = (n <= 0);
        const float inv = 1.0f / (float)(empty ? 1 : n);
        men[bi][g] = make_float4((a0.x+a1.x)*inv, (a0.y+a1.y)*inv,
                                 (a0.z+a1.z)*inv, (a0.w+a1.w)*inv);
        men[bi][32+g] = empty ? make_float4(0.f,0.f,0.f,0.f)
            : make_float4(fmaxf(b0.x,b1.x), fmaxf(b0.y,b1.y),
                          fmaxf(b0.z,b1.z), fmaxf(b0.w,b1.w));
    }
    __syncthreads();
    const int o = tid & (TYPES - 1), h = tid >> 7;
    float acc[FBPB];
    #pragma unroll
    for (int b = 0; b < FBPB; ++b) acc[b] = 0.f;
    const float* Lrow = L + (size_t)o * (2 * D) + h * 64;
    #pragma unroll
    for (int k4 = 0; k4 < 16; ++k4) {
        const float4 lv = *reinterpret_cast<const float4*>(Lrow + 4 * k4);
        #pragma unroll
        for (int b = 0; b < FBPB; ++b) {
            const float4 mv = men[b][h * 16 + k4];
            acc[b] = fmaf(lv.x, mv.x, acc[b]);
            acc[b] = fmaf(lv.y, mv.y, acc[b]);
            acc[b] = fmaf(lv.z, mv.z, acc[b]);
            acc[b] = fmaf(lv.w, mv.w, acc[b]);
        }
    }
    if (h > 0) {
        #pragma unroll
        for (int b = 0; b < FBPB; ++b) partial[h-1][b][o] = acc[b];
    }
    __syncthreads();
    if (h == 0) {
        #pragma unroll
        for (int b = 0; b < FBPB; ++b) {
            const int bg = bag0 + b;
            if (bg < B)
                out[(size_t)bg*TYPES+o] =
                    acc[b] + partial[0][b][o] + partial[1][b][o] + partial[2][b][o];
        }
    }
}

extern "C" void kernel_launch(void* const* d_in, const int* in_sizes, int n_in,
                              void* d_out, int out_size, void* d_ws, size_t ws_size,
                              hipStream_t stream)
{
    const int*   feat = (const int*)d_in[0];
    const int*   offs = (const int*)d_in[1];
    const float* W    = (const float*)d_in[2];
    const float* L    = (const float*)d_in[3];
    float*       out  = (float*)d_out;
    int T = in_sizes[0];
    int B = in_sizes[1];

    const size_t accBytes = (size_t)B * D * (sizeof(float) + sizeof(unsigned));
    const int    nwave    = (T + TPW - 1) / TPW;
    const size_t needFull = accBytes + (size_t)nwave * sizeof(int);

    if (ws_size < accBytes) {
        const int grid = (B + FBPB - 1) / FBPB;
        embbag_fallback<<<grid, 512, 0, stream>>>(feat, offs, W, L, out, T, B);
        return;
    }

    float*    wsum = (float*)d_ws;
    unsigned* wkey = (unsigned*)((char*)d_ws + (size_t)B * D * sizeof(float));

    // ---- preferred: single cooperative dispatch ----
    {
        void* args[] = { (void*)&feat, (void*)&offs, (void*)&W, (void*)&L,
                         (void*)&out, (void*)&wsum, (void*)&wkey,
                         (void*)&T, (void*)&B };
        hipError_t err = hipLaunchCooperativeKernel(
            (const void*)fused_embbag, dim3(GRID), dim3(BLOCK),
            args, 0, stream);
        if (err == hipSuccess) return;
    }

    // ---- fallback A: 3-kernel pipeline ----
    if (ws_size >= needFull) {
        int* waveseg = (int*)((char*)d_ws + accBytes);
        const int nacc4 = (int)(accBytes / sizeof(float4));
        const int grid0 = (max(nacc4, nwave) + 255) / 256;
        k0_init<<<grid0, 256, 0, stream>>>(offs, waveseg, (float4*)d_ws, nacc4,
                                           T, B, nwave);
        const int grid1 = (nwave + 3) / 4;
        k1_gather<<<grid1, 256, 0, stream>>>(feat, offs, waveseg, W,
                                             wsum, wkey, T, B);
        const int grid2 = (B + FK2B - 1) / FK2B;
        k2_linear<<<grid2, 256, 0, stream>>>(offs, wsum, wkey, L, out, T, B);
    } else {
        const int grid = (B + FBPB - 1) / FBPB;
        embbag_fallback<<<grid, 512, 0, stream>>>(feat, offs, W, L, out, T, B);
    }
}

// Round 11
// 66.017 us; speedup vs baseline: 7.0513x; 7.0513x over previous
//
#include <hip/hip_runtime.h>
#include <cfloat>

// EmbeddingBag(mean) ++ EmbeddingBag(max) -> Linear(no bias), single dispatch.
// feat[T] i32, offs[B] i32 (sorted, offs[0]=0), W[100000][128] f32,
// L[128][256] f32 ; out: [B][128] f32
// Bag b = tokens [offs[b], offs[b+1]) (offs[B]=T); empty bag -> mean=max=0.
//
// Block = 8 consecutive bags, 512 threads (8 waves).
//  - tokens of the block's 8 bags split EVENLY across the 8 waves (ignoring
//    bag boundaries) -> block-local load balance, no grid sync needed
//  - each wave walks its chunk piecewise by segment (soffs in LDS), 8 row
//    gathers in flight, flushes per-segment partials via LDS atomics
//  - finalize mean/max in LDS, then dense [8x256]x[256x128] linear phase

constexpr int D     = 128;
constexpr int TYPES = 128;
constexpr int BPB   = 8;              // bags per block
constexpr int BLOCK = 512;            // 8 waves
constexpr int WPB   = BLOCK / 64;     // waves per block

// order-preserving float->uint key (monotone): uint-compare == float-compare
__device__ __forceinline__ unsigned fkey(float f) {
    unsigned b = __float_as_uint(f);
    return (b & 0x80000000u) ? ~b : (b | 0x80000000u);
}
__device__ __forceinline__ float funkey(unsigned k) {
    return __uint_as_float((k & 0x80000000u) ? (k & 0x7FFFFFFFu) : ~k);
}

__global__ __launch_bounds__(BLOCK, 8)
void embbag_fused(const int* __restrict__ feat, const int* __restrict__ offs,
                  const float* __restrict__ W, const float* __restrict__ L,
                  float* __restrict__ out, int T, int B)
{
    __shared__ int      soffs[BPB + 1];
    __shared__ float    ssum[BPB][D];           // 4 KB  (becomes mean)
    __shared__ unsigned skey[BPB][D];           // 4 KB  (becomes max, as float)
    __shared__ float    partial[3][BPB][TYPES]; // 12 KB

    const int tid  = threadIdx.x;
    const int wv   = tid >> 6;
    const int lane = tid & 63;
    const int slot = lane >> 5;   // 0/1: alternating tokens
    const int g    = lane & 31;   // dims 4g..4g+3
    const int bag0 = blockIdx.x * BPB;

    // ---- init LDS ----
    if (tid <= BPB) {
        const int bg = bag0 + tid;
        soffs[tid] = (bg < B) ? offs[bg] : T;
    }
    for (int e = tid; e < BPB * D; e += BLOCK) {
        (&ssum[0][0])[e] = 0.f;
        (&skey[0][0])[e] = 0u;       // key(-inf)
    }
    __syncthreads();

    const int tstart = soffs[0];
    const int nT     = soffs[BPB] - tstart;

    // ---- wave's even token chunk [c_lo, c_hi) ----
    const int c_lo = tstart + (int)(((long long)nT * wv) / WPB);
    const int c_hi = tstart + (int)(((long long)nT * (wv + 1)) / WPB);

    if (c_lo < c_hi) {
        // initial segment: last seg with soffs[seg] <= c_lo
        int seg = 0;
        while (seg < BPB - 1 && soffs[seg + 1] <= c_lo) ++seg;
        int segEnd = soffs[seg + 1];

        const float* __restrict__ Wg = W + 4 * g;

        for (int c0 = c_lo; c0 < c_hi; c0 += 64) {
            const int iend   = min(c0 + 64, c_hi);
            // subchunk token ids: one coalesced load, lane j = token c0+j
            const int idxreg = feat[min(c0 + lane, T - 1)];

            float4 s4 = make_float4(0.f, 0.f, 0.f, 0.f);
            float4 m4 = make_float4(-FLT_MAX, -FLT_MAX, -FLT_MAX, -FLT_MAX);
            bool dirty = false;
            int i = c0;

            while (true) {
                const int stop = min(iend, segEnd);
                int len = stop - i;
                if (len > 0) {
                    dirty = true;
                    // full 16-token batches: 8 gathers in flight per lane
                    for (; len >= 16; len -= 16, i += 16) {
                        int idx[8];
                        #pragma unroll
                        for (int u = 0; u < 8; ++u)
                            idx[u] = __shfl(idxreg, (i - c0) + 2 * u + slot);
                        float4 v[8];
                        #pragma unroll
                        for (int u = 0; u < 8; ++u)
                            v[u] = *reinterpret_cast<const float4*>(
                                       Wg + (size_t)idx[u] * D);
                        #pragma unroll
                        for (int u = 0; u < 8; ++u) {
                            s4.x += v[u].x; s4.y += v[u].y;
                            s4.z += v[u].z; s4.w += v[u].w;
                            m4.x = fmaxf(m4.x, v[u].x);
                            m4.y = fmaxf(m4.y, v[u].y);
                            m4.z = fmaxf(m4.z, v[u].z);
                            m4.w = fmaxf(m4.w, v[u].w);
                        }
                    }
                    if (len > 0) {   // predicated tail, 1..15 tokens
                        int idx[8]; bool val[8];
                        #pragma unroll
                        for (int u = 0; u < 8; ++u) {
                            const int t = i + 2 * u + slot;
                            val[u] = (t < stop);
                            idx[u] = __shfl(idxreg, (val[u] ? t : stop - 1) - c0);
                        }
                        float4 v[8];
                        #pragma unroll
                        for (int u = 0; u < 8; ++u)
                            v[u] = *reinterpret_cast<const float4*>(
                                       Wg + (size_t)idx[u] * D);
                        #pragma unroll
                        for (int u = 0; u < 8; ++u) {
                            s4.x += val[u] ? v[u].x : 0.f;
                            s4.y += val[u] ? v[u].y : 0.f;
                            s4.z += val[u] ? v[u].z : 0.f;
                            s4.w += val[u] ? v[u].w : 0.f;
                            m4.x = fmaxf(m4.x, val[u] ? v[u].x : -FLT_MAX);
                            m4.y = fmaxf(m4.y, val[u] ? v[u].y : -FLT_MAX);
                            m4.z = fmaxf(m4.z, val[u] ? v[u].z : -FLT_MAX);
                            m4.w = fmaxf(m4.w, val[u] ? v[u].w : -FLT_MAX);
                        }
                        i = stop;
                    }
                }

                const bool done = (i >= iend);
                if (dirty && (done || i >= segEnd)) {
                    // merge slot halves (lane ^ 32); 64-lane LDS-atomic flush
                    s4.x += __shfl_xor(s4.x, 32); s4.y += __shfl_xor(s4.y, 32);
                    s4.z += __shfl_xor(s4.z, 32); s4.w += __shfl_xor(s4.w, 32);
                    m4.x = fmaxf(m4.x, __shfl_xor(m4.x, 32));
                    m4.y = fmaxf(m4.y, __shfl_xor(m4.y, 32));
                    m4.z = fmaxf(m4.z, __shfl_xor(m4.z, 32));
                    m4.w = fmaxf(m4.w, __shfl_xor(m4.w, 32));
                    const float a0 = slot ? s4.z : s4.x;
                    const float a1 = slot ? s4.w : s4.y;
                    const float b0 = slot ? m4.z : m4.x;
                    const float b1 = slot ? m4.w : m4.y;
                    const int j = 4 * g + 2 * slot;
                    atomicAdd(&ssum[seg][j],     a0);
                    atomicAdd(&ssum[seg][j + 1], a1);
                    atomicMax(&skey[seg][j],     fkey(b0));
                    atomicMax(&skey[seg][j + 1], fkey(b1));
                    s4 = make_float4(0.f, 0.f, 0.f, 0.f);
                    m4 = make_float4(-FLT_MAX, -FLT_MAX, -FLT_MAX, -FLT_MAX);
                    dirty = false;
                }
                if (done) break;
                seg = min(seg + 1, BPB - 1);
                segEnd = soffs[seg + 1];
            }
        }
    }
    __syncthreads();

    // ---- finalize in place: ssum -> mean, skey -> max (as float) ----
    for (int e = tid; e < BPB * D; e += BLOCK) {
        const int b   = e >> 7;                 // /D
        const int cnt = soffs[b + 1] - soffs[b];
        const float inv = 1.0f / (float)max(cnt, 1);
        (&ssum[0][0])[e] *= inv;
        const float mx = (cnt > 0) ? funkey((&skey[0][0])[e]) : 0.f;
        reinterpret_cast<float*>(&skey[0][0])[e] = mx;
    }
    __syncthreads();

    // ---- linear: out[bag][o] = sum_k men[bag][k] * L[o][k] ----
    // thread -> (o = out feature, h = k-quarter of 64); 8 bags reg-blocked.
    const int o = tid & (TYPES - 1);
    const int h = tid >> 7;    // 0..3
    float acc[BPB];
    #pragma unroll
    for (int b = 0; b < BPB; ++b) acc[b] = 0.f;

    const float* Lrow = L + (size_t)o * (2 * D) + h * 64;
    #pragma unroll
    for (int k4 = 0; k4 < 16; ++k4) {
        const float4 lv = *reinterpret_cast<const float4*>(Lrow + 4 * k4);
        #pragma unroll
        for (int b = 0; b < BPB; ++b) {
            const float4 mv = (h < 2)
                ? reinterpret_cast<const float4*>(&ssum[b][0])[h * 16 + k4]
                : reinterpret_cast<const float4*>(&skey[b][0])[(h - 2) * 16 + k4];
            acc[b] = fmaf(lv.x, mv.x, acc[b]);
            acc[b] = fmaf(lv.y, mv.y, acc[b]);
            acc[b] = fmaf(lv.z, mv.z, acc[b]);
            acc[b] = fmaf(lv.w, mv.w, acc[b]);
        }
    }

    if (h > 0) {
        #pragma unroll
        for (int b = 0; b < BPB; ++b) partial[h - 1][b][o] = acc[b];
    }
    __syncthreads();
    if (h == 0) {
        #pragma unroll
        for (int b = 0; b < BPB; ++b) {
            const int bag = bag0 + b;
            if (bag < B)
                out[(size_t)bag * TYPES + o] =
                    acc[b] + partial[0][b][o] + partial[1][b][o] + partial[2][b][o];
        }
    }
}

extern "C" void kernel_launch(void* const* d_in, const int* in_sizes, int n_in,
                              void* d_out, int out_size, void* d_ws, size_t ws_size,
                              hipStream_t stream)
{
    const int*   feat = (const int*)d_in[0];
    const int*   offs = (const int*)d_in[1];
    const float* W    = (const float*)d_in[2];
    const float* L    = (const float*)d_in[3];
    float*       out  = (float*)d_out;
    const int T = in_sizes[0];
    const int B = in_sizes[1];

    const int grid = (B + BPB - 1) / BPB;
    embbag_fused<<<grid, BLOCK, 0, stream>>>(feat, offs, W, L, out, T, B);
}

// Round 12
// 64.312 us; speedup vs baseline: 7.2383x; 1.0265x over previous
//
#include <hip/hip_runtime.h>
#include <cfloat>

// EmbeddingBag(mean) ++ EmbeddingBag(max) -> Linear(no bias), single dispatch.
// feat[T] i32, offs[B] i32 (sorted, offs[0]=0), W[100000][128] f32,
// L[128][256] f32 ; out: [B][128] f32
// Bag b = tokens [offs[b], offs[b+1]) (offs[B]=T); empty bag -> mean=max=0.
//
// Block = 8 consecutive bags, 1024 threads (16 waves), grid = B/8 = 1024,
// 2 blocks/CU resident (32 waves/CU) -> 2 scheduling rounds for backfill.
//  - block's tokens split EVENLY across 16 waves (ignoring bag boundaries)
//  - wave walks its chunk piecewise by segment (soffs in LDS), 8 row-gathers
//    in flight, flushes per-segment partials via LDS atomics
//  - finalize mean/max in LDS; linear phase reads L exactly once per block

constexpr int D     = 128;
constexpr int TYPES = 128;
constexpr int BPB   = 8;              // bags per block
constexpr int BLOCK = 1024;           // 16 waves
constexpr int WPB   = BLOCK / 64;     // waves per block

// order-preserving float->uint key (monotone): uint-compare == float-compare
__device__ __forceinline__ unsigned fkey(float f) {
    unsigned b = __float_as_uint(f);
    return (b & 0x80000000u) ? ~b : (b | 0x80000000u);
}
__device__ __forceinline__ float funkey(unsigned k) {
    return __uint_as_float((k & 0x80000000u) ? (k & 0x7FFFFFFFu) : ~k);
}

__global__ __launch_bounds__(BLOCK, 2)
void embbag_fused(const int* __restrict__ feat, const int* __restrict__ offs,
                  const float* __restrict__ W, const float* __restrict__ L,
                  float* __restrict__ out, int T, int B)
{
    __shared__ int      soffs[BPB + 1];
    __shared__ float    ssum[BPB][D];           // 4 KB  (becomes mean)
    __shared__ unsigned skey[BPB][D];           // 4 KB  (becomes max, as float)
    __shared__ float    partial[7][BPB][TYPES]; // 28 KB

    const int tid  = threadIdx.x;
    const int wv   = tid >> 6;
    const int lane = tid & 63;
    const int slot = lane >> 5;   // 0/1: alternating tokens
    const int g    = lane & 31;   // dims 4g..4g+3
    const int bag0 = blockIdx.x * BPB;

    // ---- init LDS ----
    if (tid <= BPB) {
        const int bg = bag0 + tid;
        soffs[tid] = (bg < B) ? offs[bg] : T;
    }
    if (tid < BPB * D) {          // BPB*D == 1024 == BLOCK
        (&ssum[0][0])[tid] = 0.f;
        (&skey[0][0])[tid] = 0u;  // key(-inf)
    }
    __syncthreads();

    const int tstart = soffs[0];
    const int nT     = soffs[BPB] - tstart;

    // ---- wave's even token chunk [c_lo, c_hi) ----
    const int c_lo = tstart + (int)(((long long)nT * wv) / WPB);
    const int c_hi = tstart + (int)(((long long)nT * (wv + 1)) / WPB);

    if (c_lo < c_hi) {
        // initial segment: last seg with soffs[seg] <= c_lo (<=7 steps, LDS)
        int seg = 0;
        while (seg < BPB - 1 && soffs[seg + 1] <= c_lo) ++seg;
        int segEnd = soffs[seg + 1];

        const float* __restrict__ Wg = W + 4 * g;

        for (int c0 = c_lo; c0 < c_hi; c0 += 64) {
            const int iend   = min(c0 + 64, c_hi);
            // subchunk token ids: one coalesced load, lane j = token c0+j
            const int idxreg = feat[min(c0 + lane, T - 1)];

            float4 s4 = make_float4(0.f, 0.f, 0.f, 0.f);
            float4 m4 = make_float4(-FLT_MAX, -FLT_MAX, -FLT_MAX, -FLT_MAX);
            bool dirty = false;
            int i = c0;

            while (true) {
                const int stop = min(iend, segEnd);
                int len = stop - i;
                if (len > 0) {
                    dirty = true;
                    // full 16-token batches: 8 gathers in flight per lane
                    for (; len >= 16; len -= 16, i += 16) {
                        int idx[8];
                        #pragma unroll
                        for (int u = 0; u < 8; ++u)
                            idx[u] = __shfl(idxreg, (i - c0) + 2 * u + slot);
                        float4 v[8];
                        #pragma unroll
                        for (int u = 0; u < 8; ++u)
                            v[u] = *reinterpret_cast<const float4*>(
                                       Wg + (size_t)idx[u] * D);
                        #pragma unroll
                        for (int u = 0; u < 8; ++u) {
                            s4.x += v[u].x; s4.y += v[u].y;
                            s4.z += v[u].z; s4.w += v[u].w;
                            m4.x = fmaxf(m4.x, v[u].x);
                            m4.y = fmaxf(m4.y, v[u].y);
                            m4.z = fmaxf(m4.z, v[u].z);
                            m4.w = fmaxf(m4.w, v[u].w);
                        }
                    }
                    if (len > 0) {   // predicated tail, 1..15 tokens
                        int idx[8]; bool val[8];
                        #pragma unroll
                        for (int u = 0; u < 8; ++u) {
                            const int t = i + 2 * u + slot;
                            val[u] = (t < stop);
                            idx[u] = __shfl(idxreg, (val[u] ? t : stop - 1) - c0);
                        }
                        float4 v[8];
                        #pragma unroll
                        for (int u = 0; u < 8; ++u)
                            v[u] = *reinterpret_cast<const float4*>(
                                       Wg + (size_t)idx[u] * D);
                        #pragma unroll
                        for (int u = 0; u < 8; ++u) {
                            s4.x += val[u] ? v[u].x : 0.f;
                            s4.y += val[u] ? v[u].y : 0.f;
                            s4.z += val[u] ? v[u].z : 0.f;
                            s4.w += val[u] ? v[u].w : 0.f;
                            m4.x = fmaxf(m4.x, val[u] ? v[u].x : -FLT_MAX);
                            m4.y = fmaxf(m4.y, val[u] ? v[u].y : -FLT_MAX);
                            m4.z = fmaxf(m4.z, val[u] ? v[u].z : -FLT_MAX);
                            m4.w = fmaxf(m4.w, val[u] ? v[u].w : -FLT_MAX);
                        }
                        i = stop;
                    }
                }

                const bool done = (i >= iend);
                if (dirty && (done || i >= segEnd)) {
                    // merge slot halves (lane ^ 32); 64-lane LDS-atomic flush
                    s4.x += __shfl_xor(s4.x, 32); s4.y += __shfl_xor(s4.y, 32);
                    s4.z += __shfl_xor(s4.z, 32); s4.w += __shfl_xor(s4.w, 32);
                    m4.x = fmaxf(m4.x, __shfl_xor(m4.x, 32));
                    m4.y = fmaxf(m4.y, __shfl_xor(m4.y, 32));
                    m4.z = fmaxf(m4.z, __shfl_xor(m4.z, 32));
                    m4.w = fmaxf(m4.w, __shfl_xor(m4.w, 32));
                    const float a0 = slot ? s4.z : s4.x;
                    const float a1 = slot ? s4.w : s4.y;
                    const float b0 = slot ? m4.z : m4.x;
                    const float b1 = slot ? m4.w : m4.y;
                    const int j = 4 * g + 2 * slot;
                    atomicAdd(&ssum[seg][j],     a0);
                    atomicAdd(&ssum[seg][j + 1], a1);
                    atomicMax(&skey[seg][j],     fkey(b0));
                    atomicMax(&skey[seg][j + 1], fkey(b1));
                    s4 = make_float4(0.f, 0.f, 0.f, 0.f);
                    m4 = make_float4(-FLT_MAX, -FLT_MAX, -FLT_MAX, -FLT_MAX);
                    dirty = false;
                }
                if (done) break;
                seg = min(seg + 1, BPB - 1);
                segEnd = soffs[seg + 1];
            }
        }
    }
    __syncthreads();

    // ---- finalize in place: ssum -> mean, skey -> max (as float) ----
    if (tid < BPB * D) {
        const int b   = tid >> 7;               // /D
        const int cnt = soffs[b + 1] - soffs[b];
        const float inv = 1.0f / (float)max(cnt, 1);
        (&ssum[0][0])[tid] *= inv;
        const float mx = (cnt > 0) ? funkey((&skey[0][0])[tid]) : 0.f;
        reinterpret_cast<float*>(&skey[0][0])[tid] = mx;
    }
    __syncthreads();

    // ---- linear: out[bag][o] = sum_k men[bag][k] * L[o][k] ----
    // thread -> (o = out feature, h = k-eighth of 32); 8 bags reg-blocked.
    // Block reads L exactly once: 1024 threads x 128 B.
    const int o = tid & (TYPES - 1);
    const int h = tid >> 7;    // 0..7
    float acc[BPB];
    #pragma unroll
    for (int b = 0; b < BPB; ++b) acc[b] = 0.f;

    const float* Lrow = L + (size_t)o * (2 * D) + h * 32;
    #pragma unroll
    for (int k4 = 0; k4 < 8; ++k4) {
        const float4 lv = *reinterpret_cast<const float4*>(Lrow + 4 * k4);
        #pragma unroll
        for (int b = 0; b < BPB; ++b) {
            const float4 mv = (h < 4)
                ? reinterpret_cast<const float4*>(&ssum[b][0])[h * 8 + k4]
                : reinterpret_cast<const float4*>(&skey[b][0])[(h - 4) * 8 + k4];
            acc[b] = fmaf(lv.x, mv.x, acc[b]);
            acc[b] = fmaf(lv.y, mv.y, acc[b]);
            acc[b] = fmaf(lv.z, mv.z, acc[b]);
            acc[b] = fmaf(lv.w, mv.w, acc[b]);
        }
    }

    if (h > 0) {
        #pragma unroll
        for (int b = 0; b < BPB; ++b) partial[h - 1][b][o] = acc[b];
    }
    __syncthreads();
    if (h == 0) {
        #pragma unroll
        for (int b = 0; b < BPB; ++b) {
            const int bag = bag0 + b;
            if (bag < B) {
                float r = acc[b];
                #pragma unroll
                for (int q = 0; q < 7; ++q) r += partial[q][b][o];
                out[(size_t)bag * TYPES + o] = r;
            }
        }
    }
}

extern "C" void kernel_launch(void* const* d_in, const int* in_sizes, int n_in,
                              void* d_out, int out_size, void* d_ws, size_t ws_size,
                              hipStream_t stream)
{
    const int*   feat = (const int*)d_in[0];
    const int*   offs = (const int*)d_in[1];
    const float* W    = (const float*)d_in[2];
    const float* L    = (const float*)d_in[3];
    float*       out  = (float*)d_out;
    const int T = in_sizes[0];
    const int B = in_sizes[1];

    const int grid = (B + BPB - 1) / BPB;
    embbag_fused<<<grid, BLOCK, 0, stream>>>(feat, offs, W, L, out, T, B);
}